// Round 5
// baseline (497.949 us; speedup 1.0000x reference)
//
#include <hip/hip_runtime.h>
#include <hip/hip_bf16.h>
#include <math.h>

// ---- problem constants ----
#define T_TOK  4096      // B*S tokens
#define H_DIM  1024
#define E_NUM  8
#define FF_DIM 4096
#define KSEL   2
#define SLOTS  (T_TOK*KSEL)     // 8192
#define SLOTS_PAD (SLOTS + 256) // 256-tile overrun pad
#define BM 128
#define MAXTILES 72             // 128-row tiles
#define MAXT256  40             // 256-row tiles

typedef __attribute__((ext_vector_type(8))) short s16x8;
typedef __attribute__((ext_vector_type(8))) unsigned short u16x8;
typedef __attribute__((ext_vector_type(4))) float f32x4;

typedef __attribute__((address_space(1))) const void global_cvoid;
typedef __attribute__((address_space(3))) void lds_void;

__device__ __forceinline__ unsigned short f2bf(float f){
  unsigned int u = __float_as_uint(f);
  u += 0x7fffu + ((u>>16)&1u);
  return (unsigned short)(u>>16);
}
__device__ __forceinline__ float bf2f(unsigned short h){
  return __uint_as_float(((unsigned int)h)<<16);
}

// ---- workspace layout ----
static constexpr size_t OFF_CNT   = 0;                 // 8 ints
static constexpr size_t OFF_OFFS  = 256;               // 9 ints
static constexpr size_t OFF_NT    = 512;               // int
static constexpr size_t OFF_NT256 = 516;               // int
static constexpr size_t OFF_TILES = 768;               // 72 ints
static constexpr size_t OFF_T256  = 1088;              // 40 ints
static constexpr size_t OFF_IDX   = 1280;              // [T][2] int
static constexpr size_t OFF_POS   = OFF_IDX  + 32768;
static constexpr size_t OFF_WV    = OFF_POS  + 32768;
static constexpr size_t OFF_SLOT  = OFF_WV   + 32768;
static constexpr size_t OFF_TOK   = OFF_SLOT + 32768;
static constexpr size_t OFF_WOF   = OFF_TOK  + 32768;
static constexpr size_t OFF_XG    = OFF_WOF  + 32768;                       // [SLOTS_PAD][H] bf16
static constexpr size_t OFF_W1T   = OFF_XG  + (size_t)SLOTS_PAD*H_DIM*2;    // [E][FF][H] bf16
static constexpr size_t OFF_W2T   = OFF_W1T + (size_t)E_NUM*H_DIM*FF_DIM*2; // [E][H][FF] bf16
static constexpr size_t OFF_MID   = OFF_W2T + (size_t)E_NUM*H_DIM*FF_DIM*2; // [SLOTS_PAD][FF] bf16
static constexpr size_t OFF_Y     = OFF_MID + (size_t)SLOTS_PAD*FF_DIM*2;   // [SLOTS][H] bf16

// ---- gating ----
__global__ __launch_bounds__(64) void gate_kernel(
    const float* __restrict__ x, const float* __restrict__ Wg,
    const float* __restrict__ bg, int* __restrict__ cnt,
    int* __restrict__ idxp, int* __restrict__ posp, float* __restrict__ wvp)
{
  int t = blockIdx.x, lane = threadIdx.x;
  const float* xr = x + (size_t)t*H_DIM;
  float acc[E_NUM];
  #pragma unroll
  for (int e=0;e<E_NUM;e++) acc[e]=0.f;
  for (int i=0;i<H_DIM/64;i++){
    int h = i*64 + lane;
    float xv = xr[h];
    const float* wr_ = Wg + (size_t)h*E_NUM;
    #pragma unroll
    for (int e=0;e<E_NUM;e++) acc[e] += xv*wr_[e];
  }
  #pragma unroll
  for (int e=0;e<E_NUM;e++){
    #pragma unroll
    for (int off=32; off>0; off>>=1) acc[e] += __shfl_xor(acc[e], off);
  }
  if (lane==0){
    float l[E_NUM];
    #pragma unroll
    for (int e=0;e<E_NUM;e++) l[e] = acc[e] + bg[e];
    int i0 = 0;
    #pragma unroll
    for (int e=1;e<E_NUM;e++) if (l[e] > l[i0]) i0 = e;
    int i1 = (i0==0)?1:0;
    #pragma unroll
    for (int e=0;e<E_NUM;e++) if (e!=i0 && l[e] > l[i1]) i1 = e;
    float p1 = expf(l[i1]-l[i0]);
    float s  = 1.f + p1;
    float w0 = 1.f/s, w1 = p1/s;
    int pos0 = atomicAdd(&cnt[i0],1);
    int pos1 = atomicAdd(&cnt[i1],1);
    idxp[t*2]=i0; idxp[t*2+1]=i1;
    posp[t*2]=pos0; posp[t*2+1]=pos1;
    wvp[t*2]=w0; wvp[t*2+1]=w1;
  }
}

// ---- plan: prefix sums + both tile worklists ----
__global__ void plan_kernel(const int* __restrict__ cnt, int* __restrict__ offs,
                            int* __restrict__ tiles, int* __restrict__ ntiles,
                            int* __restrict__ tiles256, int* __restrict__ ntiles256)
{
  int o=0, n=0, n2=0;
  for (int e=0;e<E_NUM;e++){
    offs[e]=o;
    int c=cnt[e];
    int nt=(c+BM-1)/BM;
    for (int m=0;m<nt;m++) tiles[n++] = (e<<16)|m;
    int nt2=(c+255)/256;
    for (int m=0;m<nt2;m++) tiles256[n2++] = (e<<16)|m;
    o+=c;
  }
  offs[E_NUM]=o;
  *ntiles=n;
  *ntiles256=n2;
}

// ---- scatter ----
__global__ void scatter_kernel(const int* __restrict__ idxp, const int* __restrict__ posp,
                               const float* __restrict__ wvp, const int* __restrict__ offs,
                               int* __restrict__ tok_of, float* __restrict__ w_of,
                               int* __restrict__ slot_of)
{
  int i = blockIdx.x*blockDim.x + threadIdx.x;
  if (i >= SLOTS) return;
  int t = i>>1, k = i&1;
  int e = idxp[t*2+k];
  int slot = offs[e] + posp[t*2+k];
  tok_of[slot] = t;
  w_of[slot]   = wvp[t*2+k];
  slot_of[t*2+k] = slot;
}

// ---- gather ----
__global__ __launch_bounds__(256) void gather_kernel(
    const float* __restrict__ x, const int* __restrict__ tok_of,
    unsigned short* __restrict__ Xg)
{
  int slot = blockIdx.x;
  int t = tok_of[slot];
  const float4* src = (const float4*)(x + (size_t)t*H_DIM);
  float4 v = src[threadIdx.x];
  ushort4 o;
  o.x=f2bf(v.x); o.y=f2bf(v.y); o.z=f2bf(v.z); o.w=f2bf(v.w);
  ((ushort4*)(Xg + (size_t)slot*H_DIM))[threadIdx.x] = o;
}

// ---- transpose + convert ----
__global__ __launch_bounds__(256) void transconv_kernel(
    const float* __restrict__ in, unsigned short* __restrict__ out, int R, int C)
{
  __shared__ float tile[64][65];
  int e = blockIdx.z;
  const float* inp = in + (size_t)e*R*C;
  unsigned short* op = out + (size_t)e*R*C;
  int c0 = blockIdx.x*64, r0 = blockIdx.y*64;
  int tx = threadIdx.x & 15, ty = threadIdx.x >> 4;
  #pragma unroll
  for (int i=0;i<4;i++){
    int r = i*16 + ty;
    float4 v = *(const float4*)(inp + (size_t)(r0+r)*C + c0 + tx*4);
    tile[r][tx*4+0]=v.x; tile[r][tx*4+1]=v.y; tile[r][tx*4+2]=v.z; tile[r][tx*4+3]=v.w;
  }
  __syncthreads();
  int wx = threadIdx.x & 7;
  int wcl = threadIdx.x >> 3;
  #pragma unroll
  for (int i=0;i<2;i++){
    int c = i*32 + wcl;
    u16x8 o;
    #pragma unroll
    for (int j=0;j<8;j++) o[j] = f2bf(tile[wx*8+j][c]);
    *(u16x8*)(op + (size_t)(c0+c)*R + r0 + wx*8) = o;
  }
}

#define GLDS(g, l) __builtin_amdgcn_global_load_lds((global_cvoid*)(g), (lds_void*)(l), 16, 0, 0)

// ==== unified grouped GEMM: 256x256 tile, BK=64, 512 thr (8 waves 2Mx4N),
// 4 phases/K-tile (m-pairs), T2 chunk swizzle (0 bank conflicts), early stage
// issue (B@p0, A@p1 of previous tile), counted vmcnt(8)/(2), setprio.
// MODE 0: gelu epilogue (GEMM1). MODE 1: gate-scale epilogue (GEMM2). ====
template<int MODE>
__global__ __launch_bounds__(512, 2) void gemm256_kernel(
    const unsigned short* __restrict__ A,    // [rows][K]
    const unsigned short* __restrict__ Bt,   // [E][N][K]
    const float* __restrict__ bias,          // [E][N]
    unsigned short* __restrict__ Out,        // [rows][N]
    const int* __restrict__ tiles256, const int* __restrict__ ntiles256,
    const int* __restrict__ cnt, const int* __restrict__ offs,
    const float* __restrict__ w_of,
    int N, int K, int cshift)
{
  int tile_id = blockIdx.x >> cshift;
  if (tile_id >= *ntiles256) return;
  int col0 = (blockIdx.x & ((1<<cshift)-1)) << 8;
  int packed = tiles256[tile_id];
  int e = packed>>16, mt = packed & 0xffff;
  int row0 = offs[e] + mt*256;
  int nvalid = cnt[e] - mt*256; if (nvalid > 256) nvalid = 256;
  const unsigned short* Be = Bt + (size_t)e*N*K;

  __shared__ unsigned short As[2][256*64];   // 32 KB x2
  __shared__ unsigned short Bs[2][256*64];   // 32 KB x2

  int t = threadIdx.x;
  int wid = t>>6, lane = t&63;
  int wm = wid>>2, wn = wid&3;
  int fr = lane&15, fq = lane>>4;

  // staging geometry: unit = 64 rows x 128 B = 8 KB = 1 gload/thread.
  int rl  = t>>3;                 // row-local 0..63
  int ccl = (t&7) ^ (rl&7);       // inverse-swizzled chunk to fetch
  char* asb = (char*)&As[0][0];
  char* bsb = (char*)&Bs[0][0];
  int ldst = wid*1024;            // wave-uniform base inside unit

  #define STAGE_B(buf,j,kt) GLDS(Be + (size_t)(col0 + (j)*64 + rl)*K + (kt)*64 + ccl*8, \
                                 bsb + (buf)*32768 + (j)*8192 + ldst)
  #define STAGE_A(buf,j,kt) GLDS(A  + (size_t)(row0 + (j)*64 + rl)*K + (kt)*64 + ccl*8, \
                                 asb + (buf)*32768 + (j)*8192 + ldst)

  // swizzled ds_read of one 8-bf16 fragment (row base multiple of 16 -> row&7 == fr&7)
  #define RD_A(buf,m,ks) (*(const s16x8*)(asb + (buf)*32768 + (wm*128+(m)*16+fr)*128 + ((((ks)*4+fq) ^ (fr&7))<<4)))
  #define RD_B(buf,n,ks) (*(const s16x8*)(bsb + (buf)*32768 + (wn*64 +(n)*16+fr)*128 + ((((ks)*4+fq) ^ (fr&7))<<4)))

  f32x4 acc[8][4];
  #pragma unroll
  for (int i=0;i<8;i++)
    #pragma unroll
    for (int j=0;j<4;j++) acc[i][j] = (f32x4){0.f,0.f,0.f,0.f};

  s16x8 bfr[4][2];

  #define MFMA_PAIR(m0, a00,a01,a10,a11) \
    _Pragma("unroll") \
    for (int n=0;n<4;n++){ \
      acc[m0][n]   = __builtin_amdgcn_mfma_f32_16x16x32_bf16(a00, bfr[n][0], acc[m0][n],   0,0,0); \
      acc[m0][n]   = __builtin_amdgcn_mfma_f32_16x16x32_bf16(a01, bfr[n][1], acc[m0][n],   0,0,0); \
      acc[m0+1][n] = __builtin_amdgcn_mfma_f32_16x16x32_bf16(a10, bfr[n][0], acc[m0+1][n], 0,0,0); \
      acc[m0+1][n] = __builtin_amdgcn_mfma_f32_16x16x32_bf16(a11, bfr[n][1], acc[m0+1][n], 0,0,0); \
    }

  int NT = K >> 6;
  // prologue: stage tile 0 (B, A02, A13 order); B+A02 landed, A13 in flight
  STAGE_B(0,0,0); STAGE_B(0,1,0); STAGE_B(0,2,0); STAGE_B(0,3,0);
  STAGE_A(0,0,0); STAGE_A(0,2,0); STAGE_A(0,1,0); STAGE_A(0,3,0);
  asm volatile("s_waitcnt vmcnt(2)" ::: "memory");
  __builtin_amdgcn_s_barrier();

  for (int kt=0; kt<NT; ++kt){
    int cur = kt&1, nxt = cur^1;
    bool pf = (kt+1 < NT);
    // ---------- phase 0: B frags (all) + A m0,m1; stage next B ----------
    {
      #pragma unroll
      for (int n=0;n<4;n++){ bfr[n][0] = RD_B(cur,n,0); bfr[n][1] = RD_B(cur,n,1); }
      s16x8 a00=RD_A(cur,0,0), a01=RD_A(cur,0,1), a10=RD_A(cur,1,0), a11=RD_A(cur,1,1);
      if (pf){ STAGE_B(nxt,0,kt+1); STAGE_B(nxt,1,kt+1); STAGE_B(nxt,2,kt+1); STAGE_B(nxt,3,kt+1); }
      asm volatile("s_waitcnt lgkmcnt(0)" ::: "memory");
      __builtin_amdgcn_sched_barrier(0);
      __builtin_amdgcn_s_setprio(1);
      MFMA_PAIR(0, a00,a01,a10,a11);
      __builtin_amdgcn_s_setprio(0);
      __builtin_amdgcn_s_barrier();
    }
    // ---------- phase 1: A m2,m3; stage next A (units 0,2 then 1,3) ----------
    {
      s16x8 a00=RD_A(cur,2,0), a01=RD_A(cur,2,1), a10=RD_A(cur,3,0), a11=RD_A(cur,3,1);
      if (pf){ STAGE_A(nxt,0,kt+1); STAGE_A(nxt,2,kt+1); STAGE_A(nxt,1,kt+1); STAGE_A(nxt,3,kt+1); }
      asm volatile("s_waitcnt lgkmcnt(0)" ::: "memory");
      __builtin_amdgcn_sched_barrier(0);
      __builtin_amdgcn_s_setprio(1);
      MFMA_PAIR(2, a00,a01,a10,a11);
      __builtin_amdgcn_s_setprio(0);
      // retire A13 of tile kt (needed by phase 2); keep next tile's 8 in flight
      if (pf) asm volatile("s_waitcnt vmcnt(8)" ::: "memory");
      else    asm volatile("s_waitcnt vmcnt(0)" ::: "memory");
      __builtin_amdgcn_s_barrier();
    }
    // ---------- phase 2: A m4,m5 ----------
    {
      s16x8 a00=RD_A(cur,4,0), a01=RD_A(cur,4,1), a10=RD_A(cur,5,0), a11=RD_A(cur,5,1);
      asm volatile("s_waitcnt lgkmcnt(0)" ::: "memory");
      __builtin_amdgcn_sched_barrier(0);
      __builtin_amdgcn_s_setprio(1);
      MFMA_PAIR(4, a00,a01,a10,a11);
      __builtin_amdgcn_s_setprio(0);
      __builtin_amdgcn_s_barrier();
    }
    // ---------- phase 3: A m6,m7; retire next tile's B+A02 ----------
    {
      s16x8 a00=RD_A(cur,6,0), a01=RD_A(cur,6,1), a10=RD_A(cur,7,0), a11=RD_A(cur,7,1);
      asm volatile("s_waitcnt lgkmcnt(0)" ::: "memory");
      __builtin_amdgcn_sched_barrier(0);
      __builtin_amdgcn_s_setprio(1);
      MFMA_PAIR(6, a00,a01,a10,a11);
      __builtin_amdgcn_s_setprio(0);
      if (pf) asm volatile("s_waitcnt vmcnt(2)" ::: "memory");
      __builtin_amdgcn_s_barrier();
    }
  }

  // epilogue
  float bias_v[4];
  #pragma unroll
  for (int n=0;n<4;n++) bias_v[n] = bias[(size_t)e*N + col0 + wn*64 + n*16 + fr];
  #pragma unroll
  for (int m=0;m<8;m++){
    #pragma unroll
    for (int r=0;r<4;r++){
      int lrow = wm*128 + m*16 + fq*4 + r;
      if (lrow < nvalid){
        int grow = row0 + lrow;
        float scale = (MODE==1) ? w_of[grow] : 0.f;
        #pragma unroll
        for (int n=0;n<4;n++){
          int col = col0 + wn*64 + n*16 + fr;
          float v = acc[m][n][r] + bias_v[n];
          if (MODE==0) v = 0.5f*v*(1.f + erff(v*0.70710678118654752f));
          else         v *= scale;
          Out[(size_t)grow*N + col] = f2bf(v);
        }
      }
    }
  }
  #undef STAGE_B
  #undef STAGE_A
  #undef RD_A
  #undef RD_B
  #undef MFMA_PAIR
}

// ---- combine ----
__global__ __launch_bounds__(256) void combine_kernel(
    const unsigned short* __restrict__ y, const int* __restrict__ slot_of,
    float* __restrict__ out)
{
  int tok = blockIdx.x;
  int s0 = slot_of[tok*2], s1 = slot_of[tok*2+1];
  const ushort4* y0 = (const ushort4*)(y + (size_t)s0*H_DIM);
  const ushort4* y1 = (const ushort4*)(y + (size_t)s1*H_DIM);
  float4* o = (float4*)(out + (size_t)tok*H_DIM);
  ushort4 a = y0[threadIdx.x], b = y1[threadIdx.x];
  float4 r;
  r.x = bf2f(a.x)+bf2f(b.x);
  r.y = bf2f(a.y)+bf2f(b.y);
  r.z = bf2f(a.z)+bf2f(b.z);
  r.w = bf2f(a.w)+bf2f(b.w);
  o[threadIdx.x] = r;
}

extern "C" void kernel_launch(void* const* d_in, const int* in_sizes, int n_in,
                              void* d_out, int out_size, void* d_ws, size_t ws_size,
                              hipStream_t stream) {
  const float* x  = (const float*)d_in[0];
  const float* Wg = (const float*)d_in[1];
  const float* bg = (const float*)d_in[2];
  const float* W1 = (const float*)d_in[3];
  const float* b1 = (const float*)d_in[4];
  const float* W2 = (const float*)d_in[5];
  const float* b2 = (const float*)d_in[6];
  float* out = (float*)d_out;
  char* ws = (char*)d_ws;

  int*   cnt      = (int*)  (ws + OFF_CNT);
  int*   offs     = (int*)  (ws + OFF_OFFS);
  int*   ntiles   = (int*)  (ws + OFF_NT);
  int*   ntiles256= (int*)  (ws + OFF_NT256);
  int*   tiles    = (int*)  (ws + OFF_TILES);
  int*   tiles256 = (int*)  (ws + OFF_T256);
  int*   idxp     = (int*)  (ws + OFF_IDX);
  int*   posp     = (int*)  (ws + OFF_POS);
  float* wvp      = (float*)(ws + OFF_WV);
  int*   slot_of  = (int*)  (ws + OFF_SLOT);
  int*   tok_of   = (int*)  (ws + OFF_TOK);
  float* w_of     = (float*)(ws + OFF_WOF);
  unsigned short* Xg  = (unsigned short*)(ws + OFF_XG);
  unsigned short* W1t = (unsigned short*)(ws + OFF_W1T);
  unsigned short* W2t = (unsigned short*)(ws + OFF_W2T);
  unsigned short* mid = (unsigned short*)(ws + OFF_MID);
  unsigned short* y   = (unsigned short*)(ws + OFF_Y);

  hipMemsetAsync(ws + OFF_CNT, 0, 32, stream);

  gate_kernel<<<T_TOK, 64, 0, stream>>>(x, Wg, bg, cnt, idxp, posp, wvp);
  plan_kernel<<<1, 1, 0, stream>>>(cnt, offs, tiles, ntiles, tiles256, ntiles256);
  scatter_kernel<<<SLOTS/256, 256, 0, stream>>>(idxp, posp, wvp, offs, tok_of, w_of, slot_of);
  gather_kernel<<<SLOTS, 256, 0, stream>>>(x, tok_of, Xg);

  transconv_kernel<<<dim3(FF_DIM/64, H_DIM/64, E_NUM), 256, 0, stream>>>(W1, W1t, H_DIM, FF_DIM);
  transconv_kernel<<<dim3(H_DIM/64, FF_DIM/64, E_NUM), 256, 0, stream>>>(W2, W2t, FF_DIM, H_DIM);

  // GEMM1: mid = gelu(Xg @ W1[e] + b1[e]); K=1024, N=4096 (16 col-blocks)
  gemm256_kernel<0><<<dim3(MAXT256*16), 512, 0, stream>>>(
      Xg, W1t, b1, mid, tiles256, ntiles256, cnt, offs, nullptr, FF_DIM, H_DIM, 4);
  // GEMM2: y = (mid @ W2[e] + b2[e]) * gate_w; K=4096, N=1024 (4 col-blocks)
  gemm256_kernel<1><<<dim3(MAXT256*4), 512, 0, stream>>>(
      mid, W2t, b2, y, tiles256, ntiles256, cnt, offs, w_of, H_DIM, FF_DIM, 2);

  combine_kernel<<<T_TOK, 256, 0, stream>>>(y, slot_of, out);
}

// Round 6
// 488.238 us; speedup vs baseline: 1.0199x; 1.0199x over previous
//
#include <hip/hip_runtime.h>
#include <hip/hip_bf16.h>
#include <math.h>

// ---- problem constants ----
#define T_TOK  4096      // B*S tokens
#define H_DIM  1024
#define E_NUM  8
#define FF_DIM 4096
#define KSEL   2
#define SLOTS  (T_TOK*KSEL)     // 8192
#define SLOTS_PAD (SLOTS + 256) // 256-tile overrun pad
#define BM 128
#define MAXTILES 72             // 128-row tiles
#define MAXT256  40             // 256-row tiles

typedef __attribute__((ext_vector_type(8))) short s16x8;
typedef __attribute__((ext_vector_type(8))) unsigned short u16x8;
typedef __attribute__((ext_vector_type(4))) float f32x4;

typedef __attribute__((address_space(1))) const void global_cvoid;
typedef __attribute__((address_space(3))) void lds_void;

__device__ __forceinline__ unsigned short f2bf(float f){
  unsigned int u = __float_as_uint(f);
  u += 0x7fffu + ((u>>16)&1u);
  return (unsigned short)(u>>16);
}
__device__ __forceinline__ float bf2f(unsigned short h){
  return __uint_as_float(((unsigned int)h)<<16);
}

// ---- workspace layout ----
static constexpr size_t OFF_CNT   = 0;                 // 8 ints
static constexpr size_t OFF_OFFS  = 256;               // 9 ints
static constexpr size_t OFF_NT    = 512;               // int
static constexpr size_t OFF_NT256 = 516;               // int
static constexpr size_t OFF_TILES = 768;               // 72 ints
static constexpr size_t OFF_T256  = 1088;              // 40 ints
static constexpr size_t OFF_IDX   = 1280;              // [T][2] int
static constexpr size_t OFF_POS   = OFF_IDX  + 32768;
static constexpr size_t OFF_WV    = OFF_POS  + 32768;
static constexpr size_t OFF_SLOT  = OFF_WV   + 32768;
static constexpr size_t OFF_TOK   = OFF_SLOT + 32768;
static constexpr size_t OFF_WOF   = OFF_TOK  + 32768;
static constexpr size_t OFF_XG    = OFF_WOF  + 32768;                       // [SLOTS_PAD][H] bf16
static constexpr size_t OFF_W1T   = OFF_XG  + (size_t)SLOTS_PAD*H_DIM*2;    // [E][FF][H] bf16
static constexpr size_t OFF_W2T   = OFF_W1T + (size_t)E_NUM*H_DIM*FF_DIM*2; // [E][H][FF] bf16
static constexpr size_t OFF_MID   = OFF_W2T + (size_t)E_NUM*H_DIM*FF_DIM*2; // [SLOTS_PAD][FF] bf16
static constexpr size_t OFF_Y     = OFF_MID + (size_t)SLOTS_PAD*FF_DIM*2;   // [SLOTS][H] bf16

// ---- gating ----
__global__ __launch_bounds__(64) void gate_kernel(
    const float* __restrict__ x, const float* __restrict__ Wg,
    const float* __restrict__ bg, int* __restrict__ cnt,
    int* __restrict__ idxp, int* __restrict__ posp, float* __restrict__ wvp)
{
  int t = blockIdx.x, lane = threadIdx.x;
  const float* xr = x + (size_t)t*H_DIM;
  float acc[E_NUM];
  #pragma unroll
  for (int e=0;e<E_NUM;e++) acc[e]=0.f;
  for (int i=0;i<H_DIM/64;i++){
    int h = i*64 + lane;
    float xv = xr[h];
    const float* wr_ = Wg + (size_t)h*E_NUM;
    #pragma unroll
    for (int e=0;e<E_NUM;e++) acc[e] += xv*wr_[e];
  }
  #pragma unroll
  for (int e=0;e<E_NUM;e++){
    #pragma unroll
    for (int off=32; off>0; off>>=1) acc[e] += __shfl_xor(acc[e], off);
  }
  if (lane==0){
    float l[E_NUM];
    #pragma unroll
    for (int e=0;e<E_NUM;e++) l[e] = acc[e] + bg[e];
    int i0 = 0;
    #pragma unroll
    for (int e=1;e<E_NUM;e++) if (l[e] > l[i0]) i0 = e;
    int i1 = (i0==0)?1:0;
    #pragma unroll
    for (int e=0;e<E_NUM;e++) if (e!=i0 && l[e] > l[i1]) i1 = e;
    float p1 = expf(l[i1]-l[i0]);
    float s  = 1.f + p1;
    float w0 = 1.f/s, w1 = p1/s;
    int pos0 = atomicAdd(&cnt[i0],1);
    int pos1 = atomicAdd(&cnt[i1],1);
    idxp[t*2]=i0; idxp[t*2+1]=i1;
    posp[t*2]=pos0; posp[t*2+1]=pos1;
    wvp[t*2]=w0; wvp[t*2+1]=w1;
  }
}

// ---- plan ----
__global__ void plan_kernel(const int* __restrict__ cnt, int* __restrict__ offs,
                            int* __restrict__ tiles, int* __restrict__ ntiles,
                            int* __restrict__ tiles256, int* __restrict__ ntiles256)
{
  int o=0, n=0, n2=0;
  for (int e=0;e<E_NUM;e++){
    offs[e]=o;
    int c=cnt[e];
    int nt=(c+BM-1)/BM;
    for (int m=0;m<nt;m++) tiles[n++] = (e<<16)|m;
    int nt2=(c+255)/256;
    for (int m=0;m<nt2;m++) tiles256[n2++] = (e<<16)|m;
    o+=c;
  }
  offs[E_NUM]=o;
  *ntiles=n;
  *ntiles256=n2;
}

// ---- scatter ----
__global__ void scatter_kernel(const int* __restrict__ idxp, const int* __restrict__ posp,
                               const float* __restrict__ wvp, const int* __restrict__ offs,
                               int* __restrict__ tok_of, float* __restrict__ w_of,
                               int* __restrict__ slot_of)
{
  int i = blockIdx.x*blockDim.x + threadIdx.x;
  if (i >= SLOTS) return;
  int t = i>>1, k = i&1;
  int e = idxp[t*2+k];
  int slot = offs[e] + posp[t*2+k];
  tok_of[slot] = t;
  w_of[slot]   = wvp[t*2+k];
  slot_of[t*2+k] = slot;
}

// ---- gather ----
__global__ __launch_bounds__(256) void gather_kernel(
    const float* __restrict__ x, const int* __restrict__ tok_of,
    unsigned short* __restrict__ Xg)
{
  int slot = blockIdx.x;
  int t = tok_of[slot];
  const float4* src = (const float4*)(x + (size_t)t*H_DIM);
  float4 v = src[threadIdx.x];
  ushort4 o;
  o.x=f2bf(v.x); o.y=f2bf(v.y); o.z=f2bf(v.z); o.w=f2bf(v.w);
  ((ushort4*)(Xg + (size_t)slot*H_DIM))[threadIdx.x] = o;
}

// ---- transpose + convert ----
__global__ __launch_bounds__(256) void transconv_kernel(
    const float* __restrict__ in, unsigned short* __restrict__ out, int R, int C)
{
  __shared__ float tile[64][65];
  int e = blockIdx.z;
  const float* inp = in + (size_t)e*R*C;
  unsigned short* op = out + (size_t)e*R*C;
  int c0 = blockIdx.x*64, r0 = blockIdx.y*64;
  int tx = threadIdx.x & 15, ty = threadIdx.x >> 4;
  #pragma unroll
  for (int i=0;i<4;i++){
    int r = i*16 + ty;
    float4 v = *(const float4*)(inp + (size_t)(r0+r)*C + c0 + tx*4);
    tile[r][tx*4+0]=v.x; tile[r][tx*4+1]=v.y; tile[r][tx*4+2]=v.z; tile[r][tx*4+3]=v.w;
  }
  __syncthreads();
  int wx = threadIdx.x & 7;
  int wcl = threadIdx.x >> 3;
  #pragma unroll
  for (int i=0;i<2;i++){
    int c = i*32 + wcl;
    u16x8 o;
    #pragma unroll
    for (int j=0;j<8;j++) o[j] = f2bf(tile[wx*8+j][c]);
    *(u16x8*)(op + (size_t)(c0+c)*R + r0 + wx*8) = o;
  }
}

#define GLDS(g, l) __builtin_amdgcn_global_load_lds((global_cvoid*)(g), (lds_void*)(l), 16, 0, 0)

// ==== grouped GEMM: 256x256, BK=64, 8 waves (2Mx4N), 4 ks-split phases/K-tile.
// LDS regions [buf][ks][256 rows][64B], region-granular staging (each region
// staged in the slot right after its last reader), exact counted vmcnt.
// MODE 0: gelu epilogue. MODE 1: gate-scale epilogue. ====
template<int MODE>
__global__ __launch_bounds__(512, 2) void gemm256p8_kernel(
    const unsigned short* __restrict__ A,    // [rows][K]
    const unsigned short* __restrict__ Bt,   // [E][N][K]
    const float* __restrict__ bias,          // [E][N]
    unsigned short* __restrict__ Out,        // [rows][N]
    const int* __restrict__ tiles256, const int* __restrict__ ntiles256,
    const int* __restrict__ cnt, const int* __restrict__ offs,
    const float* __restrict__ w_of,
    int N, int K, int cshift)
{
  int tile_id = blockIdx.x >> cshift;
  if (tile_id >= *ntiles256) return;
  int col0 = (blockIdx.x & ((1<<cshift)-1)) << 8;
  int packed = tiles256[tile_id];
  int e = packed>>16, mt = packed & 0xffff;
  int row0 = offs[e] + mt*256;
  int nvalid = cnt[e] - mt*256; if (nvalid > 256) nvalid = 256;
  const unsigned short* Be = Bt + (size_t)e*N*K;

  __shared__ unsigned char AsRaw[65536];   // [2 buf][2 ks][16 KB region]
  __shared__ unsigned char BsRaw[65536];
  char* asb = (char*)AsRaw;
  char* bsb = (char*)BsRaw;

  int t = threadIdx.x;
  int wid = t>>6, lane = t&63;
  int wm = wid>>2, wn = wid&3;
  int fr = lane&15, fq = lane>>4;

  // staging constants: thread t writes phys cell t (16B) of an 8KB half-region.
  // phys cell = row-stripe layout with chunk swizzle (c2 + (row>>2))&3.
  int srow = ((t>>6)<<4) + ((t>>2)&15);      // row within 128-row half
  int scol = (((t&3) - ((t>>4)&3)) & 3) * 8; // inverse-swizzled k-chunk (elems)
  int sdst = (t>>6)<<10;                      // wid*1024, wave-uniform

  // read offset within a region stripe: row fr, chunk fq, swizzled
  int lane_rd = fr*64 + (((fq + (fr>>2)) & 3) << 4);

  auto stageA = [&](int buf, int ks, int kt){
    GLDS(A + (size_t)(row0 + srow)*K + kt*64 + ks*32 + scol,
         asb + buf*32768 + ks*16384 + sdst);
    GLDS(A + (size_t)(row0 + 128 + srow)*K + kt*64 + ks*32 + scol,
         asb + buf*32768 + ks*16384 + 8192 + sdst);
  };
  auto stageB = [&](int buf, int ks, int kt){
    GLDS(Be + (size_t)(col0 + srow)*K + kt*64 + ks*32 + scol,
         bsb + buf*32768 + ks*16384 + sdst);
    GLDS(Be + (size_t)(col0 + 128 + srow)*K + kt*64 + ks*32 + scol,
         bsb + buf*32768 + ks*16384 + 8192 + sdst);
  };

  f32x4 acc[8][4];
  #pragma unroll
  for (int i=0;i<8;i++)
    #pragma unroll
    for (int j=0;j<4;j++) acc[i][j] = (f32x4){0.f,0.f,0.f,0.f};
  s16x8 bfr[4];

  int NT = K >> 6;
  // prologue: stage tiles 0,1 in slot order; retire tile0's B[ks0]+A[ks0]
  stageB(0,0,0); stageA(0,0,0); stageB(0,1,0); stageA(0,1,0);
  stageB(1,0,1); stageA(1,0,1); stageB(1,1,1); stageA(1,1,1);
  asm volatile("s_waitcnt vmcnt(12)" ::: "memory");
  __builtin_amdgcn_s_barrier();

  for (int kt=0; kt<NT; ++kt){
    int cur = kt&1, nxt = cur^1;
    const char* Ac = asb + cur*32768;
    const char* Bc = bsb + cur*32768;
    bool s2 = (kt+2 < NT);
    // ---- p0: ks0, m0-3 (+B ks0); slot: A[ks1](kt+1) -> nxt ----
    {
      #pragma unroll
      for (int n=0;n<4;n++) bfr[n] = *(const s16x8*)(Bc + (wn*4+n)*1024 + lane_rd);
      s16x8 af[4];
      #pragma unroll
      for (int i=0;i<4;i++) af[i] = *(const s16x8*)(Ac + (wm*8+i)*1024 + lane_rd);
      if (kt>=1 && kt+1<NT) stageA(nxt, 1, kt+1);
      __builtin_amdgcn_s_barrier();
      asm volatile("s_waitcnt lgkmcnt(0)" ::: "memory");
      __builtin_amdgcn_sched_barrier(0);
      __builtin_amdgcn_s_setprio(1);
      #pragma unroll
      for (int i=0;i<4;i++)
        #pragma unroll
        for (int n=0;n<4;n++)
          acc[i][n] = __builtin_amdgcn_mfma_f32_16x16x32_bf16(af[i], bfr[n], acc[i][n], 0,0,0);
      __builtin_amdgcn_s_setprio(0);
      __builtin_amdgcn_s_barrier();
    }
    // ---- p1: ks0, m4-7; slot: B[ks0](kt+2) -> cur; counted wait ----
    {
      s16x8 af[4];
      #pragma unroll
      for (int i=0;i<4;i++) af[i] = *(const s16x8*)(Ac + (wm*8+4+i)*1024 + lane_rd);
      if (s2) stageB(cur, 0, kt+2);
      __builtin_amdgcn_s_barrier();
      asm volatile("s_waitcnt lgkmcnt(0)" ::: "memory");
      __builtin_amdgcn_sched_barrier(0);
      __builtin_amdgcn_s_setprio(1);
      #pragma unroll
      for (int i=0;i<4;i++)
        #pragma unroll
        for (int n=0;n<4;n++)
          acc[4+i][n] = __builtin_amdgcn_mfma_f32_16x16x32_bf16(af[i], bfr[n], acc[4+i][n], 0,0,0);
      __builtin_amdgcn_s_setprio(0);
      if (s2)             asm volatile("s_waitcnt vmcnt(10)" ::: "memory");
      else if (kt+1 < NT) asm volatile("s_waitcnt vmcnt(8)" ::: "memory");
      else                asm volatile("s_waitcnt vmcnt(0)" ::: "memory");
      __builtin_amdgcn_s_barrier();
    }
    // ---- p2: ks1, m0-3 (+B ks1); slot: A[ks0](kt+2) -> cur ----
    {
      #pragma unroll
      for (int n=0;n<4;n++) bfr[n] = *(const s16x8*)(Bc + 16384 + (wn*4+n)*1024 + lane_rd);
      s16x8 af[4];
      #pragma unroll
      for (int i=0;i<4;i++) af[i] = *(const s16x8*)(Ac + 16384 + (wm*8+i)*1024 + lane_rd);
      if (s2) stageA(cur, 0, kt+2);
      __builtin_amdgcn_s_barrier();
      asm volatile("s_waitcnt lgkmcnt(0)" ::: "memory");
      __builtin_amdgcn_sched_barrier(0);
      __builtin_amdgcn_s_setprio(1);
      #pragma unroll
      for (int i=0;i<4;i++)
        #pragma unroll
        for (int n=0;n<4;n++)
          acc[i][n] = __builtin_amdgcn_mfma_f32_16x16x32_bf16(af[i], bfr[n], acc[i][n], 0,0,0);
      __builtin_amdgcn_s_setprio(0);
      __builtin_amdgcn_s_barrier();
    }
    // ---- p3: ks1, m4-7; slot: B[ks1](kt+2) -> cur; counted wait ----
    {
      s16x8 af[4];
      #pragma unroll
      for (int i=0;i<4;i++) af[i] = *(const s16x8*)(Ac + 16384 + (wm*8+4+i)*1024 + lane_rd);
      if (s2) stageB(cur, 1, kt+2);
      __builtin_amdgcn_s_barrier();
      asm volatile("s_waitcnt lgkmcnt(0)" ::: "memory");
      __builtin_amdgcn_sched_barrier(0);
      __builtin_amdgcn_s_setprio(1);
      #pragma unroll
      for (int i=0;i<4;i++)
        #pragma unroll
        for (int n=0;n<4;n++)
          acc[4+i][n] = __builtin_amdgcn_mfma_f32_16x16x32_bf16(af[i], bfr[n], acc[4+i][n], 0,0,0);
      __builtin_amdgcn_s_setprio(0);
      if (s2)             asm volatile("s_waitcnt vmcnt(10)" ::: "memory");
      else if (kt+1 < NT) asm volatile("s_waitcnt vmcnt(4)" ::: "memory");
      __builtin_amdgcn_s_barrier();
    }
  }

  // epilogue
  float bias_v[4];
  #pragma unroll
  for (int n=0;n<4;n++) bias_v[n] = bias[(size_t)e*N + col0 + wn*64 + n*16 + fr];
  #pragma unroll
  for (int m=0;m<8;m++){
    #pragma unroll
    for (int r=0;r<4;r++){
      int lrow = wm*128 + m*16 + fq*4 + r;
      if (lrow < nvalid){
        int grow = row0 + lrow;
        float scale = (MODE==1) ? w_of[grow] : 0.f;
        #pragma unroll
        for (int n=0;n<4;n++){
          int col = col0 + wn*64 + n*16 + fr;
          float v = acc[m][n][r] + bias_v[n];
          if (MODE==0) v = 0.5f*v*(1.f + erff(v*0.70710678118654752f));
          else         v *= scale;
          Out[(size_t)grow*N + col] = f2bf(v);
        }
      }
    }
  }
}

// ---- combine ----
__global__ __launch_bounds__(256) void combine_kernel(
    const unsigned short* __restrict__ y, const int* __restrict__ slot_of,
    float* __restrict__ out)
{
  int tok = blockIdx.x;
  int s0 = slot_of[tok*2], s1 = slot_of[tok*2+1];
  const ushort4* y0 = (const ushort4*)(y + (size_t)s0*H_DIM);
  const ushort4* y1 = (const ushort4*)(y + (size_t)s1*H_DIM);
  float4* o = (float4*)(out + (size_t)tok*H_DIM);
  ushort4 a = y0[threadIdx.x], b = y1[threadIdx.x];
  float4 r;
  r.x = bf2f(a.x)+bf2f(b.x);
  r.y = bf2f(a.y)+bf2f(b.y);
  r.z = bf2f(a.z)+bf2f(b.z);
  r.w = bf2f(a.w)+bf2f(b.w);
  o[threadIdx.x] = r;
}

extern "C" void kernel_launch(void* const* d_in, const int* in_sizes, int n_in,
                              void* d_out, int out_size, void* d_ws, size_t ws_size,
                              hipStream_t stream) {
  const float* x  = (const float*)d_in[0];
  const float* Wg = (const float*)d_in[1];
  const float* bg = (const float*)d_in[2];
  const float* W1 = (const float*)d_in[3];
  const float* b1 = (const float*)d_in[4];
  const float* W2 = (const float*)d_in[5];
  const float* b2 = (const float*)d_in[6];
  float* out = (float*)d_out;
  char* ws = (char*)d_ws;

  int*   cnt      = (int*)  (ws + OFF_CNT);
  int*   offs     = (int*)  (ws + OFF_OFFS);
  int*   ntiles   = (int*)  (ws + OFF_NT);
  int*   ntiles256= (int*)  (ws + OFF_NT256);
  int*   tiles    = (int*)  (ws + OFF_TILES);
  int*   tiles256 = (int*)  (ws + OFF_T256);
  int*   idxp     = (int*)  (ws + OFF_IDX);
  int*   posp     = (int*)  (ws + OFF_POS);
  float* wvp      = (float*)(ws + OFF_WV);
  int*   slot_of  = (int*)  (ws + OFF_SLOT);
  int*   tok_of   = (int*)  (ws + OFF_TOK);
  float* w_of     = (float*)(ws + OFF_WOF);
  unsigned short* Xg  = (unsigned short*)(ws + OFF_XG);
  unsigned short* W1t = (unsigned short*)(ws + OFF_W1T);
  unsigned short* W2t = (unsigned short*)(ws + OFF_W2T);
  unsigned short* mid = (unsigned short*)(ws + OFF_MID);
  unsigned short* y   = (unsigned short*)(ws + OFF_Y);

  hipMemsetAsync(ws + OFF_CNT, 0, 32, stream);

  gate_kernel<<<T_TOK, 64, 0, stream>>>(x, Wg, bg, cnt, idxp, posp, wvp);
  plan_kernel<<<1, 1, 0, stream>>>(cnt, offs, tiles, ntiles, tiles256, ntiles256);
  scatter_kernel<<<SLOTS/256, 256, 0, stream>>>(idxp, posp, wvp, offs, tok_of, w_of, slot_of);
  gather_kernel<<<SLOTS, 256, 0, stream>>>(x, tok_of, Xg);

  transconv_kernel<<<dim3(FF_DIM/64, H_DIM/64, E_NUM), 256, 0, stream>>>(W1, W1t, H_DIM, FF_DIM);
  transconv_kernel<<<dim3(H_DIM/64, FF_DIM/64, E_NUM), 256, 0, stream>>>(W2, W2t, FF_DIM, H_DIM);

  // GEMM1: mid = gelu(Xg @ W1[e] + b1[e]); K=1024 (NT=16), N=4096 (16 col-blocks)
  gemm256p8_kernel<0><<<dim3(MAXT256*16), 512, 0, stream>>>(
      Xg, W1t, b1, mid, tiles256, ntiles256, cnt, offs, nullptr, FF_DIM, H_DIM, 4);
  // GEMM2: y = (mid @ W2[e] + b2[e]) * gate_w; K=4096 (NT=64), N=1024 (4 col-blocks)
  gemm256p8_kernel<1><<<dim3(MAXT256*4), 512, 0, stream>>>(
      mid, W2t, b2, y, tiles256, ntiles256, cnt, offs, w_of, H_DIM, FF_DIM, 2);

  combine_kernel<<<T_TOK, 256, 0, stream>>>(y, slot_of, out);
}

// Round 7
// 463.548 us; speedup vs baseline: 1.0742x; 1.0533x over previous
//
#include <hip/hip_runtime.h>
#include <hip/hip_bf16.h>
#include <math.h>

// ---- problem constants ----
#define T_TOK  4096      // B*S tokens
#define H_DIM  1024
#define E_NUM  8
#define FF_DIM 4096
#define KSEL   2
#define SLOTS  (T_TOK*KSEL)     // 8192
#define SLOTS_PAD (SLOTS + 256)
#define BM 128
#define MAXTILES 72             // 128-row tiles

typedef __attribute__((ext_vector_type(8))) short s16x8;
typedef __attribute__((ext_vector_type(8))) unsigned short u16x8;
typedef __attribute__((ext_vector_type(4))) float f32x4;

typedef __attribute__((address_space(1))) const void global_cvoid;
typedef __attribute__((address_space(3))) void lds_void;

__device__ __forceinline__ unsigned short f2bf(float f){
  unsigned int u = __float_as_uint(f);
  u += 0x7fffu + ((u>>16)&1u);
  return (unsigned short)(u>>16);
}
__device__ __forceinline__ float bf2f(unsigned short h){
  return __uint_as_float(((unsigned int)h)<<16);
}

// ---- workspace layout ----
static constexpr size_t OFF_CNT   = 0;
static constexpr size_t OFF_OFFS  = 256;
static constexpr size_t OFF_NT    = 512;
static constexpr size_t OFF_TILES = 768;
static constexpr size_t OFF_IDX   = 1280;
static constexpr size_t OFF_POS   = OFF_IDX  + 32768;
static constexpr size_t OFF_WV    = OFF_POS  + 32768;
static constexpr size_t OFF_SLOT  = OFF_WV   + 32768;
static constexpr size_t OFF_TOK   = OFF_SLOT + 32768;
static constexpr size_t OFF_WOF   = OFF_TOK  + 32768;
static constexpr size_t OFF_XG    = OFF_WOF  + 32768;                       // [SLOTS_PAD][H] bf16
static constexpr size_t OFF_W1T   = OFF_XG  + (size_t)SLOTS_PAD*H_DIM*2;    // [E][FF][H] bf16
static constexpr size_t OFF_W2T   = OFF_W1T + (size_t)E_NUM*H_DIM*FF_DIM*2; // [E][H][FF] bf16
static constexpr size_t OFF_MID   = OFF_W2T + (size_t)E_NUM*H_DIM*FF_DIM*2; // [SLOTS_PAD][FF] bf16
static constexpr size_t OFF_Y     = OFF_MID + (size_t)SLOTS_PAD*FF_DIM*2;   // [SLOTS][H] bf16

// ---- gating ----
__global__ __launch_bounds__(64) void gate_kernel(
    const float* __restrict__ x, const float* __restrict__ Wg,
    const float* __restrict__ bg, int* __restrict__ cnt,
    int* __restrict__ idxp, int* __restrict__ posp, float* __restrict__ wvp)
{
  int t = blockIdx.x, lane = threadIdx.x;
  const float* xr = x + (size_t)t*H_DIM;
  float acc[E_NUM];
  #pragma unroll
  for (int e=0;e<E_NUM;e++) acc[e]=0.f;
  for (int i=0;i<H_DIM/64;i++){
    int h = i*64 + lane;
    float xv = xr[h];
    const float* wr_ = Wg + (size_t)h*E_NUM;
    #pragma unroll
    for (int e=0;e<E_NUM;e++) acc[e] += xv*wr_[e];
  }
  #pragma unroll
  for (int e=0;e<E_NUM;e++){
    #pragma unroll
    for (int off=32; off>0; off>>=1) acc[e] += __shfl_xor(acc[e], off);
  }
  if (lane==0){
    float l[E_NUM];
    #pragma unroll
    for (int e=0;e<E_NUM;e++) l[e] = acc[e] + bg[e];
    int i0 = 0;
    #pragma unroll
    for (int e=1;e<E_NUM;e++) if (l[e] > l[i0]) i0 = e;
    int i1 = (i0==0)?1:0;
    #pragma unroll
    for (int e=0;e<E_NUM;e++) if (e!=i0 && l[e] > l[i1]) i1 = e;
    float p1 = expf(l[i1]-l[i0]);
    float s  = 1.f + p1;
    float w0 = 1.f/s, w1 = p1/s;
    int pos0 = atomicAdd(&cnt[i0],1);
    int pos1 = atomicAdd(&cnt[i1],1);
    idxp[t*2]=i0; idxp[t*2+1]=i1;
    posp[t*2]=pos0; posp[t*2+1]=pos1;
    wvp[t*2]=w0; wvp[t*2+1]=w1;
  }
}

// ---- plan ----
__global__ void plan_kernel(const int* __restrict__ cnt, int* __restrict__ offs,
                            int* __restrict__ tiles, int* __restrict__ ntiles)
{
  int o=0, n=0;
  for (int e=0;e<E_NUM;e++){
    offs[e]=o;
    int c=cnt[e];
    int nt=(c+BM-1)/BM;
    for (int m=0;m<nt;m++) tiles[n++] = (e<<16)|m;
    o+=c;
  }
  offs[E_NUM]=o;
  *ntiles=n;
}

// ---- scatter ----
__global__ void scatter_kernel(const int* __restrict__ idxp, const int* __restrict__ posp,
                               const float* __restrict__ wvp, const int* __restrict__ offs,
                               int* __restrict__ tok_of, float* __restrict__ w_of,
                               int* __restrict__ slot_of)
{
  int i = blockIdx.x*blockDim.x + threadIdx.x;
  if (i >= SLOTS) return;
  int t = i>>1, k = i&1;
  int e = idxp[t*2+k];
  int slot = offs[e] + posp[t*2+k];
  tok_of[slot] = t;
  w_of[slot]   = wvp[t*2+k];
  slot_of[t*2+k] = slot;
}

// ---- gather ----
__global__ __launch_bounds__(256) void gather_kernel(
    const float* __restrict__ x, const int* __restrict__ tok_of,
    unsigned short* __restrict__ Xg)
{
  int slot = blockIdx.x;
  int t = tok_of[slot];
  const float4* src = (const float4*)(x + (size_t)t*H_DIM);
  float4 v = src[threadIdx.x];
  ushort4 o;
  o.x=f2bf(v.x); o.y=f2bf(v.y); o.z=f2bf(v.z); o.w=f2bf(v.w);
  ((ushort4*)(Xg + (size_t)slot*H_DIM))[threadIdx.x] = o;
}

// ---- transpose + convert ----
__global__ __launch_bounds__(256) void transconv_kernel(
    const float* __restrict__ in, unsigned short* __restrict__ out, int R, int C)
{
  __shared__ float tile[64][65];
  int e = blockIdx.z;
  const float* inp = in + (size_t)e*R*C;
  unsigned short* op = out + (size_t)e*R*C;
  int c0 = blockIdx.x*64, r0 = blockIdx.y*64;
  int tx = threadIdx.x & 15, ty = threadIdx.x >> 4;
  #pragma unroll
  for (int i=0;i<4;i++){
    int r = i*16 + ty;
    float4 v = *(const float4*)(inp + (size_t)(r0+r)*C + c0 + tx*4);
    tile[r][tx*4+0]=v.x; tile[r][tx*4+1]=v.y; tile[r][tx*4+2]=v.z; tile[r][tx*4+3]=v.w;
  }
  __syncthreads();
  int wx = threadIdx.x & 7;
  int wcl = threadIdx.x >> 3;
  #pragma unroll
  for (int i=0;i<2;i++){
    int c = i*32 + wcl;
    u16x8 o;
    #pragma unroll
    for (int j=0;j<8;j++) o[j] = f2bf(tile[wx*8+j][c]);
    *(u16x8*)(op + (size_t)(c0+c)*R + r0 + wx*8) = o;
  }
}

#define GLDS(g, l) __builtin_amdgcn_global_load_lds((global_cvoid*)(g), (lds_void*)(l), 16, 0, 0)

// ==== grouped GEMM, m97 configuration + occupancy: 128x128, BK=32, 256 thr,
// dbuf 32 KB LDS, depth-2 counted vmcnt(4), 2-way-max swizzle, <=128 VGPR
// (launch_bounds(256,4)) -> target 4 waves/SIMD, ~4 blocks/CU.
// MODE 0: gelu epilogue. MODE 1: gate-scale epilogue. ====
template<int MODE>
__global__ __launch_bounds__(256, 4) void gemm128_kernel(
    const unsigned short* __restrict__ A,    // [rows][K]
    const unsigned short* __restrict__ Bt,   // [E][N][K]
    const float* __restrict__ bias,          // [E][N]
    unsigned short* __restrict__ Out,        // [rows][N]
    const int* __restrict__ tiles, const int* __restrict__ ntiles,
    const int* __restrict__ cnt, const int* __restrict__ offs,
    const float* __restrict__ w_of,
    int N, int K, int cshift)
{
  int tile_id = blockIdx.x >> cshift;
  if (tile_id >= *ntiles) return;
  int col0 = (blockIdx.x & ((1<<cshift)-1)) << 7;
  int packed = tiles[tile_id];
  int e = packed>>16, mt = packed & 0xffff;
  int row0 = offs[e] + mt*BM;
  int nvalid = cnt[e] - mt*BM; if (nvalid > BM) nvalid = BM;
  const unsigned short* Be = Bt + (size_t)e*N*K;

  // dbuf linear-ish LDS with chunk swizzle: [buf][128 rows][4 chunks of 16B]
  __shared__ unsigned short As[2][128*32];
  __shared__ unsigned short Bs[2][128*32];
  char* asb = (char*)&As[0][0];
  char* bsb = (char*)&Bs[0][0];

  int t = threadIdx.x;
  int wid = t>>6, lane = t&63;
  int wr = (wid>>1)*64, wc = (wid&1)*64;
  int fr = lane&15, fq = lane>>4;

  // staging: sweep = 4 KB = 64 rows x 64 B; thread t -> row t>>2, phys chunk t&3.
  // stored logical chunk: c_log = (c_phys - ((row>>1)&3)) & 3  (2-way-max swizzle)
  int srow = t>>2;
  int sclog = ((t&3) - ((t>>3)&3)) & 3;
  int sdst = wid*1024;                       // wave-uniform; +lane*16 implicit

  // per-lane global bases (k0=0): A sweeps rows srow, 64+srow; B same on cols
  const unsigned short* gA0 = A  + (size_t)(row0 + srow)*K      + sclog*8;
  const unsigned short* gA1 = A  + (size_t)(row0 + 64 + srow)*K + sclog*8;
  const unsigned short* gB0 = Be + (size_t)(col0 + srow)*K      + sclog*8;
  const unsigned short* gB1 = Be + (size_t)(col0 + 64 + srow)*K + sclog*8;

  auto stage = [&](int buf, int kelem){
    GLDS(gA0 + kelem, asb + buf*8192 + sdst);
    GLDS(gA1 + kelem, asb + buf*8192 + 4096 + sdst);
    GLDS(gB0 + kelem, bsb + buf*8192 + sdst);
    GLDS(gB1 + kelem, bsb + buf*8192 + 4096 + sdst);
  };

  // read offset for fragment row r (r%16==fr pattern): byte = r*64 + swz(fq,r)*16
  int rd_sw = ((fq + ((fr>>1)&3)) & 3) << 4;   // phys chunk byte offset

  f32x4 acc[4][4];
  #pragma unroll
  for (int i=0;i<4;i++)
    #pragma unroll
    for (int j=0;j<4;j++) acc[i][j] = (f32x4){0.f,0.f,0.f,0.f};

  int NT = K >> 5;
  stage(0, 0);
  stage(1, 32);
  for (int kt=0; kt<NT; ++kt){
    int cur = kt&1;
    if (kt+1 < NT) asm volatile("s_waitcnt vmcnt(4)" ::: "memory");
    else           asm volatile("s_waitcnt vmcnt(0)" ::: "memory");
    __builtin_amdgcn_s_barrier();
    asm volatile("" ::: "memory");

    s16x8 af[4], bfr[4];
    #pragma unroll
    for (int i=0;i<4;i++){
      af[i]  = *(const s16x8*)(asb + cur*8192 + (wr + i*16 + fr)*64 + rd_sw);
      bfr[i] = *(const s16x8*)(bsb + cur*8192 + (wc + i*16 + fr)*64 + rd_sw);
    }
    #pragma unroll
    for (int i=0;i<4;i++)
      #pragma unroll
      for (int j=0;j<4;j++)
        acc[i][j] = __builtin_amdgcn_mfma_f32_16x16x32_bf16(af[i], bfr[j], acc[i][j], 0,0,0);

    asm volatile("s_waitcnt lgkmcnt(0)" ::: "memory");
    __builtin_amdgcn_s_barrier();
    asm volatile("" ::: "memory");
    if (kt+2 < NT) stage(cur, (kt+2)*32);
  }

  // epilogue: C/D layout col=lane&15, row=(lane>>4)*4+reg
  #pragma unroll
  for (int i=0;i<4;i++){
    #pragma unroll
    for (int r=0;r<4;r++){
      int lrow = wr + i*16 + fq*4 + r;
      if (lrow < nvalid){
        int grow = row0 + lrow;
        float scale = (MODE==1) ? w_of[grow] : 0.f;
        #pragma unroll
        for (int j=0;j<4;j++){
          int col = col0 + wc + j*16 + fr;
          float v = acc[i][j][r] + bias[(size_t)e*N + col];
          if (MODE==0) v = 0.5f*v*(1.f + erff(v*0.70710678118654752f));
          else         v *= scale;
          Out[(size_t)grow*N + col] = f2bf(v);
        }
      }
    }
  }
}

// ---- combine ----
__global__ __launch_bounds__(256) void combine_kernel(
    const unsigned short* __restrict__ y, const int* __restrict__ slot_of,
    float* __restrict__ out)
{
  int tok = blockIdx.x;
  int s0 = slot_of[tok*2], s1 = slot_of[tok*2+1];
  const ushort4* y0 = (const ushort4*)(y + (size_t)s0*H_DIM);
  const ushort4* y1 = (const ushort4*)(y + (size_t)s1*H_DIM);
  float4* o = (float4*)(out + (size_t)tok*H_DIM);
  ushort4 a = y0[threadIdx.x], b = y1[threadIdx.x];
  float4 r;
  r.x = bf2f(a.x)+bf2f(b.x);
  r.y = bf2f(a.y)+bf2f(b.y);
  r.z = bf2f(a.z)+bf2f(b.z);
  r.w = bf2f(a.w)+bf2f(b.w);
  o[threadIdx.x] = r;
}

extern "C" void kernel_launch(void* const* d_in, const int* in_sizes, int n_in,
                              void* d_out, int out_size, void* d_ws, size_t ws_size,
                              hipStream_t stream) {
  const float* x  = (const float*)d_in[0];
  const float* Wg = (const float*)d_in[1];
  const float* bg = (const float*)d_in[2];
  const float* W1 = (const float*)d_in[3];
  const float* b1 = (const float*)d_in[4];
  const float* W2 = (const float*)d_in[5];
  const float* b2 = (const float*)d_in[6];
  float* out = (float*)d_out;
  char* ws = (char*)d_ws;

  int*   cnt      = (int*)  (ws + OFF_CNT);
  int*   offs     = (int*)  (ws + OFF_OFFS);
  int*   ntiles   = (int*)  (ws + OFF_NT);
  int*   tiles    = (int*)  (ws + OFF_TILES);
  int*   idxp     = (int*)  (ws + OFF_IDX);
  int*   posp     = (int*)  (ws + OFF_POS);
  float* wvp      = (float*)(ws + OFF_WV);
  int*   slot_of  = (int*)  (ws + OFF_SLOT);
  int*   tok_of   = (int*)  (ws + OFF_TOK);
  float* w_of     = (float*)(ws + OFF_WOF);
  unsigned short* Xg  = (unsigned short*)(ws + OFF_XG);
  unsigned short* W1t = (unsigned short*)(ws + OFF_W1T);
  unsigned short* W2t = (unsigned short*)(ws + OFF_W2T);
  unsigned short* mid = (unsigned short*)(ws + OFF_MID);
  unsigned short* y   = (unsigned short*)(ws + OFF_Y);

  hipMemsetAsync(ws + OFF_CNT, 0, 32, stream);

  gate_kernel<<<T_TOK, 64, 0, stream>>>(x, Wg, bg, cnt, idxp, posp, wvp);
  plan_kernel<<<1, 1, 0, stream>>>(cnt, offs, tiles, ntiles);
  scatter_kernel<<<SLOTS/256, 256, 0, stream>>>(idxp, posp, wvp, offs, tok_of, w_of, slot_of);
  gather_kernel<<<SLOTS, 256, 0, stream>>>(x, tok_of, Xg);

  transconv_kernel<<<dim3(FF_DIM/64, H_DIM/64, E_NUM), 256, 0, stream>>>(W1, W1t, H_DIM, FF_DIM);
  transconv_kernel<<<dim3(H_DIM/64, FF_DIM/64, E_NUM), 256, 0, stream>>>(W2, W2t, FF_DIM, H_DIM);

  // GEMM1: mid = gelu(Xg @ W1[e] + b1[e]); K=1024 (NT=32), N=4096 (32 col-blocks)
  gemm128_kernel<0><<<dim3(MAXTILES*32), 256, 0, stream>>>(
      Xg, W1t, b1, mid, tiles, ntiles, cnt, offs, nullptr, FF_DIM, H_DIM, 5);
  // GEMM2: y = (mid @ W2[e] + b2[e]) * gate_w; K=4096 (NT=128), N=1024 (8 col-blocks)
  gemm128_kernel<1><<<dim3(MAXTILES*8), 256, 0, stream>>>(
      mid, W2t, b2, y, tiles, ntiles, cnt, offs, w_of, H_DIM, FF_DIM, 3);

  combine_kernel<<<T_TOK, 256, 0, stream>>>(y, slot_of, out);
}

// Round 8
// 445.501 us; speedup vs baseline: 1.1177x; 1.0405x over previous
//
#include <hip/hip_runtime.h>
#include <hip/hip_bf16.h>
#include <math.h>

// ---- problem constants ----
#define T_TOK  4096      // B*S tokens
#define H_DIM  1024
#define E_NUM  8
#define FF_DIM 4096
#define KSEL   2
#define SLOTS  (T_TOK*KSEL)     // 8192
#define SLOTS_PAD (SLOTS + 256)
#define BM 128
#define MAXTILES 72             // 128-row tiles (18 bands of 4)

typedef __attribute__((ext_vector_type(8))) short s16x8;
typedef __attribute__((ext_vector_type(8))) unsigned short u16x8;
typedef __attribute__((ext_vector_type(4))) float f32x4;

typedef __attribute__((address_space(1))) const void global_cvoid;
typedef __attribute__((address_space(3))) void lds_void;

__device__ __forceinline__ unsigned short f2bf(float f){
  unsigned int u = __float_as_uint(f);
  u += 0x7fffu + ((u>>16)&1u);
  return (unsigned short)(u>>16);
}
__device__ __forceinline__ float bf2f(unsigned short h){
  return __uint_as_float(((unsigned int)h)<<16);
}

// ---- workspace layout ----
static constexpr size_t OFF_CNT   = 0;
static constexpr size_t OFF_OFFS  = 256;
static constexpr size_t OFF_NT    = 512;
static constexpr size_t OFF_TILES = 768;
static constexpr size_t OFF_IDX   = 1280;
static constexpr size_t OFF_POS   = OFF_IDX  + 32768;
static constexpr size_t OFF_WV    = OFF_POS  + 32768;
static constexpr size_t OFF_SLOT  = OFF_WV   + 32768;
static constexpr size_t OFF_TOK   = OFF_SLOT + 32768;
static constexpr size_t OFF_WOF   = OFF_TOK  + 32768;
static constexpr size_t OFF_XG    = OFF_WOF  + 32768;                       // [SLOTS_PAD][H] bf16
static constexpr size_t OFF_W1T   = OFF_XG  + (size_t)SLOTS_PAD*H_DIM*2;    // [E][FF][H] bf16
static constexpr size_t OFF_W2T   = OFF_W1T + (size_t)E_NUM*H_DIM*FF_DIM*2; // [E][H][FF] bf16
static constexpr size_t OFF_MID   = OFF_W2T + (size_t)E_NUM*H_DIM*FF_DIM*2; // [SLOTS_PAD][FF] bf16
static constexpr size_t OFF_Y     = OFF_MID + (size_t)SLOTS_PAD*FF_DIM*2;   // [SLOTS][H] bf16

// ---- gating ----
__global__ __launch_bounds__(64) void gate_kernel(
    const float* __restrict__ x, const float* __restrict__ Wg,
    const float* __restrict__ bg, int* __restrict__ cnt,
    int* __restrict__ idxp, int* __restrict__ posp, float* __restrict__ wvp)
{
  int t = blockIdx.x, lane = threadIdx.x;
  const float* xr = x + (size_t)t*H_DIM;
  float acc[E_NUM];
  #pragma unroll
  for (int e=0;e<E_NUM;e++) acc[e]=0.f;
  for (int i=0;i<H_DIM/64;i++){
    int h = i*64 + lane;
    float xv = xr[h];
    const float* wr_ = Wg + (size_t)h*E_NUM;
    #pragma unroll
    for (int e=0;e<E_NUM;e++) acc[e] += xv*wr_[e];
  }
  #pragma unroll
  for (int e=0;e<E_NUM;e++){
    #pragma unroll
    for (int off=32; off>0; off>>=1) acc[e] += __shfl_xor(acc[e], off);
  }
  if (lane==0){
    float l[E_NUM];
    #pragma unroll
    for (int e=0;e<E_NUM;e++) l[e] = acc[e] + bg[e];
    int i0 = 0;
    #pragma unroll
    for (int e=1;e<E_NUM;e++) if (l[e] > l[i0]) i0 = e;
    int i1 = (i0==0)?1:0;
    #pragma unroll
    for (int e=0;e<E_NUM;e++) if (e!=i0 && l[e] > l[i1]) i1 = e;
    float p1 = expf(l[i1]-l[i0]);
    float s  = 1.f + p1;
    float w0 = 1.f/s, w1 = p1/s;
    int pos0 = atomicAdd(&cnt[i0],1);
    int pos1 = atomicAdd(&cnt[i1],1);
    idxp[t*2]=i0; idxp[t*2+1]=i1;
    posp[t*2]=pos0; posp[t*2+1]=pos1;
    wvp[t*2]=w0; wvp[t*2+1]=w1;
  }
}

// ---- plan ----
__global__ void plan_kernel(const int* __restrict__ cnt, int* __restrict__ offs,
                            int* __restrict__ tiles, int* __restrict__ ntiles)
{
  int o=0, n=0;
  for (int e=0;e<E_NUM;e++){
    offs[e]=o;
    int c=cnt[e];
    int nt=(c+BM-1)/BM;
    for (int m=0;m<nt;m++) tiles[n++] = (e<<16)|m;
    o+=c;
  }
  offs[E_NUM]=o;
  *ntiles=n;
}

// ---- scatter ----
__global__ void scatter_kernel(const int* __restrict__ idxp, const int* __restrict__ posp,
                               const float* __restrict__ wvp, const int* __restrict__ offs,
                               int* __restrict__ tok_of, float* __restrict__ w_of,
                               int* __restrict__ slot_of)
{
  int i = blockIdx.x*blockDim.x + threadIdx.x;
  if (i >= SLOTS) return;
  int t = i>>1, k = i&1;
  int e = idxp[t*2+k];
  int slot = offs[e] + posp[t*2+k];
  tok_of[slot] = t;
  w_of[slot]   = wvp[t*2+k];
  slot_of[t*2+k] = slot;
}

// ---- gather ----
__global__ __launch_bounds__(256) void gather_kernel(
    const float* __restrict__ x, const int* __restrict__ tok_of,
    unsigned short* __restrict__ Xg)
{
  int slot = blockIdx.x;
  int t = tok_of[slot];
  const float4* src = (const float4*)(x + (size_t)t*H_DIM);
  float4 v = src[threadIdx.x];
  ushort4 o;
  o.x=f2bf(v.x); o.y=f2bf(v.y); o.z=f2bf(v.z); o.w=f2bf(v.w);
  ((ushort4*)(Xg + (size_t)slot*H_DIM))[threadIdx.x] = o;
}

// ---- transpose + convert ----
__global__ __launch_bounds__(256) void transconv_kernel(
    const float* __restrict__ in, unsigned short* __restrict__ out, int R, int C)
{
  __shared__ float tile[64][65];
  int e = blockIdx.z;
  const float* inp = in + (size_t)e*R*C;
  unsigned short* op = out + (size_t)e*R*C;
  int c0 = blockIdx.x*64, r0 = blockIdx.y*64;
  int tx = threadIdx.x & 15, ty = threadIdx.x >> 4;
  #pragma unroll
  for (int i=0;i<4;i++){
    int r = i*16 + ty;
    float4 v = *(const float4*)(inp + (size_t)(r0+r)*C + c0 + tx*4);
    tile[r][tx*4+0]=v.x; tile[r][tx*4+1]=v.y; tile[r][tx*4+2]=v.z; tile[r][tx*4+3]=v.w;
  }
  __syncthreads();
  int wx = threadIdx.x & 7;
  int wcl = threadIdx.x >> 3;
  #pragma unroll
  for (int i=0;i<2;i++){
    int c = i*32 + wcl;
    u16x8 o;
    #pragma unroll
    for (int j=0;j<8;j++) o[j] = f2bf(tile[wx*8+j][c]);
    *(u16x8*)(op + (size_t)(c0+c)*R + r0 + wx*8) = o;
  }
}

#define GLDS(g, l) __builtin_amdgcn_global_load_lds((global_cvoid*)(g), (lds_void*)(l), 16, 0, 0)

// ==== grouped GEMM, r7 structure + XCD-chunked work mapping.
// Chunk = 4 tiles x 4 col-blocks = 16 blocks pinned to one XCD (blockIdx&7),
// sequenced per-XCD (blockIdx>>3). Per-chunk working set 2 MB <= 4 MB L2.
// 128x128, BK=32, 256 thr, dbuf, depth-2 counted vmcnt(4), 2-way-max swizzle.
// MODE 0: gelu epilogue. MODE 1: gate-scale epilogue. ====
template<int MODE>
__global__ __launch_bounds__(256, 4) void gemm128_kernel(
    const unsigned short* __restrict__ A,    // [rows][K]
    const unsigned short* __restrict__ Bt,   // [E][N][K]
    const float* __restrict__ bias,          // [E][N]
    unsigned short* __restrict__ Out,        // [rows][N]
    const int* __restrict__ tiles, const int* __restrict__ ntiles,
    const int* __restrict__ cnt, const int* __restrict__ offs,
    const float* __restrict__ w_of,
    int N, int K, int cpcs)                  // cpcs: log2(col-bands)
{
  // ---- chunked mapping: L -> (xcd, slot) -> (chunk, within) -> (tile, col) ----
  int L = blockIdx.x;
  int xcd = L & 7;
  int slot = L >> 3;
  int within = slot & 15;
  int chunk = ((slot >> 4) << 3) + xcd;
  int tb = chunk >> cpcs;
  int cb = chunk & ((1<<cpcs)-1);
  int tile_id = tb*4 + (within & 3);
  if (tile_id >= *ntiles) return;
  int col0 = (cb*4 + (within >> 2)) << 7;

  int packed = tiles[tile_id];
  int e = packed>>16, mt = packed & 0xffff;
  int row0 = offs[e] + mt*BM;
  int nvalid = cnt[e] - mt*BM; if (nvalid > BM) nvalid = BM;
  const unsigned short* Be = Bt + (size_t)e*N*K;

  // dbuf LDS with chunk swizzle: [buf][128 rows][4 chunks of 16B]
  __shared__ unsigned short As[2][128*32];
  __shared__ unsigned short Bs[2][128*32];
  char* asb = (char*)&As[0][0];
  char* bsb = (char*)&Bs[0][0];

  int t = threadIdx.x;
  int wid = t>>6, lane = t&63;
  int wr = (wid>>1)*64, wc = (wid&1)*64;
  int fr = lane&15, fq = lane>>4;

  // staging: sweep = 4 KB = 64 rows x 64 B; thread t -> row t>>2, phys chunk t&3.
  // stored logical chunk: c_log = (c_phys - ((row>>1)&3)) & 3  (2-way-max swizzle)
  int srow = t>>2;
  int sclog = ((t&3) - ((t>>3)&3)) & 3;
  int sdst = wid*1024;

  const unsigned short* gA0 = A  + (size_t)(row0 + srow)*K      + sclog*8;
  const unsigned short* gA1 = A  + (size_t)(row0 + 64 + srow)*K + sclog*8;
  const unsigned short* gB0 = Be + (size_t)(col0 + srow)*K      + sclog*8;
  const unsigned short* gB1 = Be + (size_t)(col0 + 64 + srow)*K + sclog*8;

  auto stage = [&](int buf, int kelem){
    GLDS(gA0 + kelem, asb + buf*8192 + sdst);
    GLDS(gA1 + kelem, asb + buf*8192 + 4096 + sdst);
    GLDS(gB0 + kelem, bsb + buf*8192 + sdst);
    GLDS(gB1 + kelem, bsb + buf*8192 + 4096 + sdst);
  };

  int rd_sw = ((fq + ((fr>>1)&3)) & 3) << 4;

  f32x4 acc[4][4];
  #pragma unroll
  for (int i=0;i<4;i++)
    #pragma unroll
    for (int j=0;j<4;j++) acc[i][j] = (f32x4){0.f,0.f,0.f,0.f};

  int NT = K >> 5;
  stage(0, 0);
  stage(1, 32);
  for (int kt=0; kt<NT; ++kt){
    int cur = kt&1;
    if (kt+1 < NT) asm volatile("s_waitcnt vmcnt(4)" ::: "memory");
    else           asm volatile("s_waitcnt vmcnt(0)" ::: "memory");
    __builtin_amdgcn_s_barrier();
    asm volatile("" ::: "memory");

    s16x8 af[4], bfr[4];
    #pragma unroll
    for (int i=0;i<4;i++){
      af[i]  = *(const s16x8*)(asb + cur*8192 + (wr + i*16 + fr)*64 + rd_sw);
      bfr[i] = *(const s16x8*)(bsb + cur*8192 + (wc + i*16 + fr)*64 + rd_sw);
    }
    #pragma unroll
    for (int i=0;i<4;i++)
      #pragma unroll
      for (int j=0;j<4;j++)
        acc[i][j] = __builtin_amdgcn_mfma_f32_16x16x32_bf16(af[i], bfr[j], acc[i][j], 0,0,0);

    asm volatile("s_waitcnt lgkmcnt(0)" ::: "memory");
    __builtin_amdgcn_s_barrier();
    asm volatile("" ::: "memory");
    if (kt+2 < NT) stage(cur, (kt+2)*32);
  }

  // epilogue: C/D layout col=lane&15, row=(lane>>4)*4+reg
  #pragma unroll
  for (int i=0;i<4;i++){
    #pragma unroll
    for (int r=0;r<4;r++){
      int lrow = wr + i*16 + fq*4 + r;
      if (lrow < nvalid){
        int grow = row0 + lrow;
        float scale = (MODE==1) ? w_of[grow] : 0.f;
        #pragma unroll
        for (int j=0;j<4;j++){
          int col = col0 + wc + j*16 + fr;
          float v = acc[i][j][r] + bias[(size_t)e*N + col];
          if (MODE==0) v = 0.5f*v*(1.f + erff(v*0.70710678118654752f));
          else         v *= scale;
          Out[(size_t)grow*N + col] = f2bf(v);
        }
      }
    }
  }
}

// ---- combine ----
__global__ __launch_bounds__(256) void combine_kernel(
    const unsigned short* __restrict__ y, const int* __restrict__ slot_of,
    float* __restrict__ out)
{
  int tok = blockIdx.x;
  int s0 = slot_of[tok*2], s1 = slot_of[tok*2+1];
  const ushort4* y0 = (const ushort4*)(y + (size_t)s0*H_DIM);
  const ushort4* y1 = (const ushort4*)(y + (size_t)s1*H_DIM);
  float4* o = (float4*)(out + (size_t)tok*H_DIM);
  ushort4 a = y0[threadIdx.x], b = y1[threadIdx.x];
  float4 r;
  r.x = bf2f(a.x)+bf2f(b.x);
  r.y = bf2f(a.y)+bf2f(b.y);
  r.z = bf2f(a.z)+bf2f(b.z);
  r.w = bf2f(a.w)+bf2f(b.w);
  o[threadIdx.x] = r;
}

extern "C" void kernel_launch(void* const* d_in, const int* in_sizes, int n_in,
                              void* d_out, int out_size, void* d_ws, size_t ws_size,
                              hipStream_t stream) {
  const float* x  = (const float*)d_in[0];
  const float* Wg = (const float*)d_in[1];
  const float* bg = (const float*)d_in[2];
  const float* W1 = (const float*)d_in[3];
  const float* b1 = (const float*)d_in[4];
  const float* W2 = (const float*)d_in[5];
  const float* b2 = (const float*)d_in[6];
  float* out = (float*)d_out;
  char* ws = (char*)d_ws;

  int*   cnt      = (int*)  (ws + OFF_CNT);
  int*   offs     = (int*)  (ws + OFF_OFFS);
  int*   ntiles   = (int*)  (ws + OFF_NT);
  int*   tiles    = (int*)  (ws + OFF_TILES);
  int*   idxp     = (int*)  (ws + OFF_IDX);
  int*   posp     = (int*)  (ws + OFF_POS);
  float* wvp      = (float*)(ws + OFF_WV);
  int*   slot_of  = (int*)  (ws + OFF_SLOT);
  int*   tok_of   = (int*)  (ws + OFF_TOK);
  float* w_of     = (float*)(ws + OFF_WOF);
  unsigned short* Xg  = (unsigned short*)(ws + OFF_XG);
  unsigned short* W1t = (unsigned short*)(ws + OFF_W1T);
  unsigned short* W2t = (unsigned short*)(ws + OFF_W2T);
  unsigned short* mid = (unsigned short*)(ws + OFF_MID);
  unsigned short* y   = (unsigned short*)(ws + OFF_Y);

  hipMemsetAsync(ws + OFF_CNT, 0, 32, stream);

  gate_kernel<<<T_TOK, 64, 0, stream>>>(x, Wg, bg, cnt, idxp, posp, wvp);
  plan_kernel<<<1, 1, 0, stream>>>(cnt, offs, tiles, ntiles);
  scatter_kernel<<<SLOTS/256, 256, 0, stream>>>(idxp, posp, wvp, offs, tok_of, w_of, slot_of);
  gather_kernel<<<SLOTS, 256, 0, stream>>>(x, tok_of, Xg);

  transconv_kernel<<<dim3(FF_DIM/64, H_DIM/64, E_NUM), 256, 0, stream>>>(W1, W1t, H_DIM, FF_DIM);
  transconv_kernel<<<dim3(H_DIM/64, FF_DIM/64, E_NUM), 256, 0, stream>>>(W2, W2t, FF_DIM, H_DIM);

  // GEMM1: 18 tile-bands x 8 col-bands = 144 chunks -> 18 chunk-rounds x 128 = 2304
  gemm128_kernel<0><<<dim3(2304), 256, 0, stream>>>(
      Xg, W1t, b1, mid, tiles, ntiles, cnt, offs, nullptr, FF_DIM, H_DIM, 3);
  // GEMM2: 18 tile-bands x 2 col-bands = 36 chunks -> ceil(36/8)=5 rounds x 128 = 640
  gemm128_kernel<1><<<dim3(640), 256, 0, stream>>>(
      mid, W2t, b2, y, tiles, ntiles, cnt, offs, w_of, H_DIM, FF_DIM, 1);

  combine_kernel<<<T_TOK, 256, 0, stream>>>(y, slot_of, out);
}